// Round 1
// baseline (591.377 us; speedup 1.0000x reference)
//
#include <hip/hip_runtime.h>

#define N_PTS 1000000
#define KS2 9
#define CIN 4
#define COUT 16
#define EPS 1e-5f
#define SLOPE 0.2f

__device__ __forceinline__ float leaky(float x) { return x >= 0.f ? x : SLOPE * x; }

// ---------------------------------------------------------------------------
// K1: y1[n,o] = sum_{j,c} data[ind[n,j],c] * w1[c,j,o] + b1[o]
// P=2 points per thread so LDS weight reads amortize over 2 FMAs each.
// ---------------------------------------------------------------------------
__global__ __launch_bounds__(256) void k_conv1(const float* __restrict__ data,
                                               const int* __restrict__ ind,
                                               const float* __restrict__ w1,
                                               const float* __restrict__ b1,
                                               float* __restrict__ y1) {
    __shared__ float wl[CIN * KS2 * COUT];
    __shared__ float bl[COUT];
    for (int t = threadIdx.x; t < CIN * KS2 * COUT; t += 256) wl[t] = w1[t];
    if (threadIdx.x < COUT) bl[threadIdx.x] = b1[threadIdx.x];
    __syncthreads();

    int p = blockIdx.x * 256 + threadIdx.x;
    int n0 = p * 2;
    if (n0 >= N_PTS) return;

    float acc0[COUT], acc1[COUT];
#pragma unroll
    for (int o = 0; o < COUT; o++) { acc0[o] = bl[o]; acc1[o] = bl[o]; }

    const float4* d4 = (const float4*)data;
#pragma unroll 1
    for (int j = 0; j < KS2; j++) {
        int i0 = ind[n0 * KS2 + j];
        int i1 = ind[n0 * KS2 + KS2 + j];
        float4 v0 = d4[i0];
        float4 v1 = d4[i1];
        float a0[4] = {v0.x, v0.y, v0.z, v0.w};
        float a1[4] = {v1.x, v1.y, v1.z, v1.w};
#pragma unroll
        for (int c = 0; c < CIN; c++) {
            const float* wr = &wl[(c * KS2 + j) * COUT];
#pragma unroll
            for (int o = 0; o < COUT; o++) {
                float w = wr[o];
                acc0[o] = fmaf(a0[c], w, acc0[o]);
                acc1[o] = fmaf(a1[c], w, acc1[o]);
            }
        }
    }

    float4* y4 = (float4*)(y1 + (size_t)n0 * COUT);
    y4[0] = make_float4(acc0[0], acc0[1], acc0[2], acc0[3]);
    y4[1] = make_float4(acc0[4], acc0[5], acc0[6], acc0[7]);
    y4[2] = make_float4(acc0[8], acc0[9], acc0[10], acc0[11]);
    y4[3] = make_float4(acc0[12], acc0[13], acc0[14], acc0[15]);
    y4[4] = make_float4(acc1[0], acc1[1], acc1[2], acc1[3]);
    y4[5] = make_float4(acc1[4], acc1[5], acc1[6], acc1[7]);
    y4[6] = make_float4(acc1[8], acc1[9], acc1[10], acc1[11]);
    y4[7] = make_float4(acc1[12], acc1[13], acc1[14], acc1[15]);
}

// ---------------------------------------------------------------------------
// Per-channel sum / sumsq over a [N,16] fp32 buffer.
// Each thread's float4 covers channels 4*(tid&3)..+3 (grid stride keeps i%4
// invariant). Butterfly over lane bits 2..5 reduces within channel-quarter.
// sums[0..15]=sum, sums[16..31]=sumsq.
// ---------------------------------------------------------------------------
__global__ __launch_bounds__(256) void k_stats(const float* __restrict__ x,
                                               float* __restrict__ sums) {
    const size_t n4 = (size_t)N_PTS * COUT / 4;
    int tid = threadIdx.x;
    int lane = tid & 63;
    int wid = tid >> 6;
    int q = tid & 3;
    size_t i = (size_t)blockIdx.x * 256 + tid;
    size_t stride = (size_t)gridDim.x * 256;
    const float4* x4 = (const float4*)x;
    float4 s = make_float4(0.f, 0.f, 0.f, 0.f);
    float4 ss = make_float4(0.f, 0.f, 0.f, 0.f);
    for (; i < n4; i += stride) {
        float4 v = x4[i];
        s.x += v.x; s.y += v.y; s.z += v.z; s.w += v.w;
        ss.x = fmaf(v.x, v.x, ss.x);
        ss.y = fmaf(v.y, v.y, ss.y);
        ss.z = fmaf(v.z, v.z, ss.z);
        ss.w = fmaf(v.w, v.w, ss.w);
    }
#pragma unroll
    for (int m = 4; m < 64; m <<= 1) {
        s.x += __shfl_xor(s.x, m);   s.y += __shfl_xor(s.y, m);
        s.z += __shfl_xor(s.z, m);   s.w += __shfl_xor(s.w, m);
        ss.x += __shfl_xor(ss.x, m); ss.y += __shfl_xor(ss.y, m);
        ss.z += __shfl_xor(ss.z, m); ss.w += __shfl_xor(ss.w, m);
    }
    __shared__ float red[4][4][8];
    if (lane < 4) {
        float* r = red[wid][q];
        r[0] = s.x;  r[1] = s.y;  r[2] = s.z;  r[3] = s.w;
        r[4] = ss.x; r[5] = ss.y; r[6] = ss.z; r[7] = ss.w;
    }
    __syncthreads();
    if (tid < 32) {
        int qq = tid >> 3, k = tid & 7;
        float v = red[0][qq][k] + red[1][qq][k] + red[2][qq][k] + red[3][qq][k];
        int c = qq * 4 + (k & 3);
        atomicAdd(&sums[(k >> 2) * 16 + c], v);
    }
}

// ---------------------------------------------------------------------------
// BN finalize: a = g * rsqrt(var+eps), b = beta - mean*a
// ---------------------------------------------------------------------------
__global__ void k_finalize(const float* __restrict__ sums,
                           const float* __restrict__ g,
                           const float* __restrict__ be,
                           float* __restrict__ ab) {
    int c = threadIdx.x;
    if (c < COUT) {
        const float invN = 1.0f / (float)N_PTS;
        float mean = sums[c] * invN;
        float var = sums[COUT + c] * invN - mean * mean;
        float a = g[c] * rsqrtf(var + EPS);
        ab[c] = a;
        ab[COUT + c] = be[c] - mean * a;
    }
}

// ---------------------------------------------------------------------------
// K3: y2[n,o] = sum_{j,c} leaky(a1[c]*y1[ind[n,j],c]+b1[c]) * w2[c,j,o]
// BN1 affine + leaky applied on the fly to each gathered row.
// ---------------------------------------------------------------------------
__global__ __launch_bounds__(256) void k_conv2(const float* __restrict__ y1,
                                               const int* __restrict__ ind,
                                               const float* __restrict__ w2,
                                               const float* __restrict__ ab1,
                                               float* __restrict__ y2) {
    __shared__ float wl[COUT * KS2 * COUT];
    __shared__ float a1s[COUT], b1s[COUT];
    for (int t = threadIdx.x; t < COUT * KS2 * COUT; t += 256) wl[t] = w2[t];
    if (threadIdx.x < COUT) {
        a1s[threadIdx.x] = ab1[threadIdx.x];
        b1s[threadIdx.x] = ab1[COUT + threadIdx.x];
    }
    __syncthreads();

    int p = blockIdx.x * 256 + threadIdx.x;
    int n0 = p * 2;
    if (n0 >= N_PTS) return;

    float acc0[COUT] = {0.f, 0.f, 0.f, 0.f, 0.f, 0.f, 0.f, 0.f,
                        0.f, 0.f, 0.f, 0.f, 0.f, 0.f, 0.f, 0.f};
    float acc1[COUT] = {0.f, 0.f, 0.f, 0.f, 0.f, 0.f, 0.f, 0.f,
                        0.f, 0.f, 0.f, 0.f, 0.f, 0.f, 0.f, 0.f};

#pragma unroll 1
    for (int j = 0; j < KS2; j++) {
        int i0 = ind[n0 * KS2 + j];
        int i1 = ind[n0 * KS2 + KS2 + j];
        const float4* r0 = (const float4*)(y1 + (size_t)i0 * COUT);
        const float4* r1 = (const float4*)(y1 + (size_t)i1 * COUT);
        float u0[COUT], u1[COUT];
#pragma unroll
        for (int k = 0; k < 4; k++) {
            float4 t0 = r0[k];
            float4 t1 = r1[k];
            float e0[4] = {t0.x, t0.y, t0.z, t0.w};
            float e1[4] = {t1.x, t1.y, t1.z, t1.w};
#pragma unroll
            for (int e = 0; e < 4; e++) {
                int c = k * 4 + e;
                u0[c] = leaky(fmaf(a1s[c], e0[e], b1s[c]));
                u1[c] = leaky(fmaf(a1s[c], e1[e], b1s[c]));
            }
        }
#pragma unroll
        for (int c = 0; c < COUT; c++) {
            const float* wr = &wl[(c * KS2 + j) * COUT];
#pragma unroll
            for (int o = 0; o < COUT; o++) {
                float w = wr[o];
                acc0[o] = fmaf(u0[c], w, acc0[o]);
                acc1[o] = fmaf(u1[c], w, acc1[o]);
            }
        }
    }

    float4* y4 = (float4*)(y2 + (size_t)n0 * COUT);
    y4[0] = make_float4(acc0[0], acc0[1], acc0[2], acc0[3]);
    y4[1] = make_float4(acc0[4], acc0[5], acc0[6], acc0[7]);
    y4[2] = make_float4(acc0[8], acc0[9], acc0[10], acc0[11]);
    y4[3] = make_float4(acc0[12], acc0[13], acc0[14], acc0[15]);
    y4[4] = make_float4(acc1[0], acc1[1], acc1[2], acc1[3]);
    y4[5] = make_float4(acc1[4], acc1[5], acc1[6], acc1[7]);
    y4[6] = make_float4(acc1[8], acc1[9], acc1[10], acc1[11]);
    y4[7] = make_float4(acc1[12], acc1[13], acc1[14], acc1[15]);
}

// ---------------------------------------------------------------------------
// K5: out[n,o] = leaky(a2[o]*y2[n,o] + b2[o] + sum_c data[n,c]*wd[o,c])
// In-place on d_out.
// ---------------------------------------------------------------------------
__global__ __launch_bounds__(256) void k_final(float* __restrict__ y2,
                                               const float* __restrict__ data,
                                               const float* __restrict__ wd,
                                               const float* __restrict__ ab2) {
    __shared__ float wds[COUT * CIN];
    __shared__ float a2s[COUT], b2s[COUT];
    if (threadIdx.x < COUT * CIN) wds[threadIdx.x] = wd[threadIdx.x];
    if (threadIdx.x < COUT) {
        a2s[threadIdx.x] = ab2[threadIdx.x];
        b2s[threadIdx.x] = ab2[COUT + threadIdx.x];
    }
    __syncthreads();

    int n = blockIdx.x * 256 + threadIdx.x;
    if (n >= N_PTS) return;

    float4 d = ((const float4*)data)[n];
    float dv[4] = {d.x, d.y, d.z, d.w};
    float4* row = (float4*)(y2 + (size_t)n * COUT);
#pragma unroll
    for (int k = 0; k < 4; k++) {
        float4 t = row[k];
        float e[4] = {t.x, t.y, t.z, t.w};
        float r[4];
#pragma unroll
        for (int eo = 0; eo < 4; eo++) {
            int o = k * 4 + eo;
            float res = dv[0] * wds[o * 4 + 0];
            res = fmaf(dv[1], wds[o * 4 + 1], res);
            res = fmaf(dv[2], wds[o * 4 + 2], res);
            res = fmaf(dv[3], wds[o * 4 + 3], res);
            float x = fmaf(a2s[o], e[eo], b2s[o]) + res;
            r[eo] = leaky(x);
        }
        row[k] = make_float4(r[0], r[1], r[2], r[3]);
    }
}

extern "C" void kernel_launch(void* const* d_in, const int* in_sizes, int n_in,
                              void* d_out, int out_size, void* d_ws, size_t ws_size,
                              hipStream_t stream) {
    const float* data = (const float*)d_in[0];
    const int* ind    = (const int*)d_in[1];
    const float* w1   = (const float*)d_in[2];
    const float* b1   = (const float*)d_in[3];
    const float* g1   = (const float*)d_in[4];
    const float* be1  = (const float*)d_in[5];
    const float* w2   = (const float*)d_in[6];
    const float* g2   = (const float*)d_in[7];
    const float* be2  = (const float*)d_in[8];
    const float* wd   = (const float*)d_in[9];
    float* out = (float*)d_out;

    float* y1 = (float*)d_ws;                      // N*16 floats = 64 MB
    float* stats = y1 + (size_t)N_PTS * COUT;      // 128 floats
    // stats layout: [0..31] sum1/sq1, [32..63] sum2/sq2, [64..95] ab1, [96..127] ab2

    hipMemsetAsync(stats, 0, 64 * sizeof(float), stream);

    int pair_blocks = (N_PTS / 2 + 255) / 256;
    int pt_blocks   = (N_PTS + 255) / 256;

    k_conv1<<<pair_blocks, 256, 0, stream>>>(data, ind, w1, b1, y1);
    k_stats<<<1024, 256, 0, stream>>>(y1, stats);
    k_finalize<<<1, 64, 0, stream>>>(stats, g1, be1, stats + 64);
    k_conv2<<<pair_blocks, 256, 0, stream>>>(y1, ind, w2, stats + 64, out);
    k_stats<<<1024, 256, 0, stream>>>(out, stats + 32);
    k_finalize<<<1, 64, 0, stream>>>(stats + 32, g2, be2, stats + 96);
    k_final<<<pt_blocks, 256, 0, stream>>>(out, data, wd, stats + 96);
}

// Round 2
// 362.580 us; speedup vs baseline: 1.6310x; 1.6310x over previous
//
#include <hip/hip_runtime.h>

#define N_PTS 1000000
#define KS2 9
#define CIN 4
#define COUT 16
#define EPS 1e-5f
#define SLOPE 0.2f

__device__ __forceinline__ float leaky(float x) { return fmaxf(x, SLOPE * x); }

__device__ __forceinline__ float blo(unsigned int u) {
    union { unsigned int i; float f; } v; v.i = u << 16; return v.f;
}
__device__ __forceinline__ float bhi(unsigned int u) {
    union { unsigned int i; float f; } v; v.i = u & 0xffff0000u; return v.f;
}
__device__ __forceinline__ unsigned int f2bf(float f) {
    union { float f; unsigned int i; } v; v.f = f;
    return (v.i + 0x7fffu + ((v.i >> 16) & 1u)) >> 16;
}
__device__ __forceinline__ unsigned int fpack(float lo, float hi) {
    return f2bf(lo) | (f2bf(hi) << 16);
}

// ---------------------------------------------------------------------------
// Convert data fp32 [N,4] -> bf16 (uint2 per row). 8 floats / thread.
// ---------------------------------------------------------------------------
__global__ __launch_bounds__(256) void k_cvt(const float* __restrict__ in,
                                             uint4* __restrict__ out) {
    int t = blockIdx.x * 256 + threadIdx.x;
    if (t >= N_PTS * CIN / 8) return;
    const float4* in4 = (const float4*)in;
    float4 a = in4[t * 2], b = in4[t * 2 + 1];
    uint4 o;
    o.x = fpack(a.x, a.y);
    o.y = fpack(a.z, a.w);
    o.z = fpack(b.x, b.y);
    o.w = fpack(b.z, b.w);
    out[t] = o;
}

// ---------------------------------------------------------------------------
// Block-level stats reduction: each thread contributes s[16], ss[16];
// result atomically added to stats[0..31].
// ---------------------------------------------------------------------------
__device__ __forceinline__ void stats_reduce(float* s, float* ss,
                                             float (*red)[32],
                                             float* stats) {
#pragma unroll
    for (int m = 1; m < 64; m <<= 1) {
#pragma unroll
        for (int o = 0; o < COUT; o++) {
            s[o] += __shfl_xor(s[o], m);
            ss[o] += __shfl_xor(ss[o], m);
        }
    }
    int lane = threadIdx.x & 63, wid = threadIdx.x >> 6;
    if (lane == 0) {
#pragma unroll
        for (int o = 0; o < COUT; o++) {
            red[wid][o] = s[o];
            red[wid][COUT + o] = ss[o];
        }
    }
    __syncthreads();
    if (threadIdx.x < 32) {
        float v = red[0][threadIdx.x] + red[1][threadIdx.x] +
                  red[2][threadIdx.x] + red[3][threadIdx.x];
        atomicAdd(&stats[threadIdx.x], v);
    }
}

// ---------------------------------------------------------------------------
// K1: y1[n,o] = sum_{j,c} data_bf[ind[n,j],c] * w1[c,j,o] + b1[o]
// P=2 points/thread; all 18 row loads issued up front. Fused BN1 stats.
// Writes y1 as bf16 (2x uint4 per row).
// ---------------------------------------------------------------------------
__global__ __launch_bounds__(256) void k_conv1(const uint2* __restrict__ dbf,
                                               const int* __restrict__ ind,
                                               const float* __restrict__ w1,
                                               const float* __restrict__ b1,
                                               uint4* __restrict__ y1bf,
                                               float* __restrict__ stats) {
    __shared__ float wl[CIN * KS2 * COUT];
    __shared__ float bl[COUT];
    __shared__ float red[4][32];
    for (int t = threadIdx.x; t < CIN * KS2 * COUT; t += 256) wl[t] = w1[t];
    if (threadIdx.x < COUT) bl[threadIdx.x] = b1[threadIdx.x];
    __syncthreads();

    int p = blockIdx.x * 256 + threadIdx.x;
    int n0 = p * 2;
    bool active = n0 < N_PTS;

    float acc0[COUT] = {0.f, 0.f, 0.f, 0.f, 0.f, 0.f, 0.f, 0.f,
                        0.f, 0.f, 0.f, 0.f, 0.f, 0.f, 0.f, 0.f};
    float acc1[COUT] = {0.f, 0.f, 0.f, 0.f, 0.f, 0.f, 0.f, 0.f,
                        0.f, 0.f, 0.f, 0.f, 0.f, 0.f, 0.f, 0.f};

    if (active) {
        int idx0[KS2], idx1[KS2];
#pragma unroll
        for (int j = 0; j < KS2; j++) {
            idx0[j] = ind[n0 * KS2 + j];
            idx1[j] = ind[n0 * KS2 + KS2 + j];
        }
        uint2 r0[KS2], r1[KS2];
#pragma unroll
        for (int j = 0; j < KS2; j++) {
            r0[j] = dbf[idx0[j]];
            r1[j] = dbf[idx1[j]];
        }
#pragma unroll
        for (int o = 0; o < COUT; o++) { acc0[o] = bl[o]; acc1[o] = bl[o]; }
#pragma unroll
        for (int j = 0; j < KS2; j++) {
            float a0[4] = {blo(r0[j].x), bhi(r0[j].x), blo(r0[j].y), bhi(r0[j].y)};
            float a1[4] = {blo(r1[j].x), bhi(r1[j].x), blo(r1[j].y), bhi(r1[j].y)};
#pragma unroll
            for (int c = 0; c < CIN; c++) {
                const float* wr = &wl[(c * KS2 + j) * COUT];
#pragma unroll
                for (int o = 0; o < COUT; o++) {
                    acc0[o] = fmaf(a0[c], wr[o], acc0[o]);
                    acc1[o] = fmaf(a1[c], wr[o], acc1[o]);
                }
            }
        }
        uint4 w0a, w0b, w1a, w1b;
        w0a.x = fpack(acc0[0], acc0[1]);   w0a.y = fpack(acc0[2], acc0[3]);
        w0a.z = fpack(acc0[4], acc0[5]);   w0a.w = fpack(acc0[6], acc0[7]);
        w0b.x = fpack(acc0[8], acc0[9]);   w0b.y = fpack(acc0[10], acc0[11]);
        w0b.z = fpack(acc0[12], acc0[13]); w0b.w = fpack(acc0[14], acc0[15]);
        w1a.x = fpack(acc1[0], acc1[1]);   w1a.y = fpack(acc1[2], acc1[3]);
        w1a.z = fpack(acc1[4], acc1[5]);   w1a.w = fpack(acc1[6], acc1[7]);
        w1b.x = fpack(acc1[8], acc1[9]);   w1b.y = fpack(acc1[10], acc1[11]);
        w1b.z = fpack(acc1[12], acc1[13]); w1b.w = fpack(acc1[14], acc1[15]);
        y1bf[(size_t)n0 * 2 + 0] = w0a;
        y1bf[(size_t)n0 * 2 + 1] = w0b;
        y1bf[(size_t)n0 * 2 + 2] = w1a;
        y1bf[(size_t)n0 * 2 + 3] = w1b;
    }

    float s[COUT], ss[COUT];
#pragma unroll
    for (int o = 0; o < COUT; o++) {
        s[o] = acc0[o] + acc1[o];
        ss[o] = acc0[o] * acc0[o] + acc1[o] * acc1[o];
    }
    stats_reduce(s, ss, red, stats);
}

// ---------------------------------------------------------------------------
// BN finalize: a = g * rsqrt(var+eps), b = beta - mean*a
// ---------------------------------------------------------------------------
__global__ void k_finalize(const float* __restrict__ sums,
                           const float* __restrict__ g,
                           const float* __restrict__ be,
                           float* __restrict__ ab) {
    int c = threadIdx.x;
    if (c < COUT) {
        const float invN = 1.0f / (float)N_PTS;
        float mean = sums[c] * invN;
        float var = sums[COUT + c] * invN - mean * mean;
        float a = g[c] * rsqrtf(var + EPS);
        ab[c] = a;
        ab[COUT + c] = be[c] - mean * a;
    }
}

// ---------------------------------------------------------------------------
// K3: y2[n,o] = sum_{j,c} leaky(a1[c]*y1[ind[n,j],c]+b1[c]) * w2[c,j,o]
// P=1; all 18 gather loads (9 rows x 2 uint4) issued up front.
// Fused BN2 stats. Writes y2 bf16.
// ---------------------------------------------------------------------------
__global__ __launch_bounds__(256) void k_conv2(const uint4* __restrict__ y1bf,
                                               const int* __restrict__ ind,
                                               const float* __restrict__ w2,
                                               const float* __restrict__ ab1,
                                               uint4* __restrict__ y2bf,
                                               float* __restrict__ stats) {
    __shared__ float wl[COUT * KS2 * COUT];
    __shared__ float a1s[COUT], b1s[COUT];
    __shared__ float red[4][32];
    for (int t = threadIdx.x; t < COUT * KS2 * COUT; t += 256) wl[t] = w2[t];
    if (threadIdx.x < COUT) {
        a1s[threadIdx.x] = ab1[threadIdx.x];
        b1s[threadIdx.x] = ab1[COUT + threadIdx.x];
    }
    __syncthreads();

    int n = blockIdx.x * 256 + threadIdx.x;
    bool active = n < N_PTS;

    float acc[COUT] = {0.f, 0.f, 0.f, 0.f, 0.f, 0.f, 0.f, 0.f,
                       0.f, 0.f, 0.f, 0.f, 0.f, 0.f, 0.f, 0.f};

    if (active) {
        int idx[KS2];
#pragma unroll
        for (int j = 0; j < KS2; j++) idx[j] = ind[n * KS2 + j];
        uint4 ra[KS2], rb[KS2];
#pragma unroll
        for (int j = 0; j < KS2; j++) {
            ra[j] = y1bf[(size_t)idx[j] * 2];
            rb[j] = y1bf[(size_t)idx[j] * 2 + 1];
        }
#pragma unroll
        for (int j = 0; j < KS2; j++) {
            float v[COUT] = {blo(ra[j].x), bhi(ra[j].x), blo(ra[j].y), bhi(ra[j].y),
                             blo(ra[j].z), bhi(ra[j].z), blo(ra[j].w), bhi(ra[j].w),
                             blo(rb[j].x), bhi(rb[j].x), blo(rb[j].y), bhi(rb[j].y),
                             blo(rb[j].z), bhi(rb[j].z), blo(rb[j].w), bhi(rb[j].w)};
            float u[COUT];
#pragma unroll
            for (int c = 0; c < COUT; c++)
                u[c] = leaky(fmaf(a1s[c], v[c], b1s[c]));
#pragma unroll
            for (int c = 0; c < COUT; c++) {
                const float* wr = &wl[(c * KS2 + j) * COUT];
#pragma unroll
                for (int o = 0; o < COUT; o++)
                    acc[o] = fmaf(u[c], wr[o], acc[o]);
            }
        }
        uint4 wa, wb;
        wa.x = fpack(acc[0], acc[1]);   wa.y = fpack(acc[2], acc[3]);
        wa.z = fpack(acc[4], acc[5]);   wa.w = fpack(acc[6], acc[7]);
        wb.x = fpack(acc[8], acc[9]);   wb.y = fpack(acc[10], acc[11]);
        wb.z = fpack(acc[12], acc[13]); wb.w = fpack(acc[14], acc[15]);
        y2bf[(size_t)n * 2 + 0] = wa;
        y2bf[(size_t)n * 2 + 1] = wb;
    }

    float s[COUT], ss[COUT];
#pragma unroll
    for (int o = 0; o < COUT; o++) {
        s[o] = acc[o];
        ss[o] = acc[o] * acc[o];
    }
    stats_reduce(s, ss, red, stats);
}

// ---------------------------------------------------------------------------
// K5: out[n,o] = leaky(a2[o]*y2[n,o] + b2[o] + sum_c data[n,c]*wd[o,c])
// ---------------------------------------------------------------------------
__global__ __launch_bounds__(256) void k_final(const uint4* __restrict__ y2bf,
                                               const float* __restrict__ data,
                                               const float* __restrict__ wd,
                                               const float* __restrict__ ab2,
                                               float4* __restrict__ out) {
    __shared__ float wds[COUT * CIN];
    __shared__ float a2s[COUT], b2s[COUT];
    if (threadIdx.x < COUT * CIN) wds[threadIdx.x] = wd[threadIdx.x];
    if (threadIdx.x < COUT) {
        a2s[threadIdx.x] = ab2[threadIdx.x];
        b2s[threadIdx.x] = ab2[COUT + threadIdx.x];
    }
    __syncthreads();

    int n = blockIdx.x * 256 + threadIdx.x;
    if (n >= N_PTS) return;

    float4 d = ((const float4*)data)[n];
    float dv[4] = {d.x, d.y, d.z, d.w};
    uint4 qa = y2bf[(size_t)n * 2], qb = y2bf[(size_t)n * 2 + 1];
    float e[COUT] = {blo(qa.x), bhi(qa.x), blo(qa.y), bhi(qa.y),
                     blo(qa.z), bhi(qa.z), blo(qa.w), bhi(qa.w),
                     blo(qb.x), bhi(qb.x), blo(qb.y), bhi(qb.y),
                     blo(qb.z), bhi(qb.z), blo(qb.w), bhi(qb.w)};
    float r[COUT];
#pragma unroll
    for (int o = 0; o < COUT; o++) {
        float res = dv[0] * wds[o * 4 + 0];
        res = fmaf(dv[1], wds[o * 4 + 1], res);
        res = fmaf(dv[2], wds[o * 4 + 2], res);
        res = fmaf(dv[3], wds[o * 4 + 3], res);
        r[o] = leaky(fmaf(a2s[o], e[o], b2s[o]) + res);
    }
    float4* row = out + (size_t)n * 4;
    row[0] = make_float4(r[0], r[1], r[2], r[3]);
    row[1] = make_float4(r[4], r[5], r[6], r[7]);
    row[2] = make_float4(r[8], r[9], r[10], r[11]);
    row[3] = make_float4(r[12], r[13], r[14], r[15]);
}

extern "C" void kernel_launch(void* const* d_in, const int* in_sizes, int n_in,
                              void* d_out, int out_size, void* d_ws, size_t ws_size,
                              hipStream_t stream) {
    const float* data = (const float*)d_in[0];
    const int* ind    = (const int*)d_in[1];
    const float* w1   = (const float*)d_in[2];
    const float* b1   = (const float*)d_in[3];
    const float* g1   = (const float*)d_in[4];
    const float* be1  = (const float*)d_in[5];
    const float* w2   = (const float*)d_in[6];
    const float* g2   = (const float*)d_in[7];
    const float* be2  = (const float*)d_in[8];
    const float* wd   = (const float*)d_in[9];

    unsigned char* ws = (unsigned char*)d_ws;
    // [0 .. 8MB): data_bf16 (dead after conv1), then reused as y2_bf16 [0 .. 32e6)
    // [32e6 .. 64e6): y1_bf16
    // [64e6 .. +512): stats: [0..31] s1, [32..63] ab1, [64..95] s2, [96..127] ab2
    uint4* dbf4  = (uint4*)ws;
    uint2* dbf2  = (uint2*)ws;
    uint4* y2bf  = (uint4*)ws;
    uint4* y1bf  = (uint4*)(ws + 32000000u);
    float* stats = (float*)(ws + 64000000u);

    hipMemsetAsync(stats, 0, 128 * sizeof(float), stream);

    int cvt_blocks  = (N_PTS * CIN / 8 + 255) / 256;   // 1954
    int pair_blocks = (N_PTS / 2 + 255) / 256;         // 1954
    int pt_blocks   = (N_PTS + 255) / 256;             // 3907

    k_cvt<<<cvt_blocks, 256, 0, stream>>>(data, dbf4);
    k_conv1<<<pair_blocks, 256, 0, stream>>>(dbf2, ind, w1, b1, y1bf, stats);
    k_finalize<<<1, 64, 0, stream>>>(stats, g1, be1, stats + 32);
    k_conv2<<<pt_blocks, 256, 0, stream>>>(y1bf, ind, w2, stats + 32, y2bf, stats + 64);
    k_finalize<<<1, 64, 0, stream>>>(stats + 64, g2, be2, stats + 96);
    k_final<<<pt_blocks, 256, 0, stream>>>(y2bf, data, wd, stats + 96, (float4*)d_out);
}

// Round 3
// 320.211 us; speedup vs baseline: 1.8468x; 1.1323x over previous
//
#include <hip/hip_runtime.h>

#define N_PTS 1000000
#define EPS 1e-5f
#define SLOPE 0.2f

typedef __attribute__((ext_vector_type(8))) short bf16x8;
typedef __attribute__((ext_vector_type(4))) float f32x4;

__device__ __forceinline__ float leaky(float x) { return fmaxf(x, SLOPE * x); }
__device__ __forceinline__ float bf2f(unsigned int u) {
    union { unsigned int i; float f; } v; v.i = u << 16; return v.f;
}
__device__ __forceinline__ unsigned int f2bf(float f) {
    union { float f; unsigned int i; } v; v.f = f;
    return (v.i + 0x7fffu + ((v.i >> 16) & 1u)) >> 16;
}
__device__ __forceinline__ unsigned int pk(float a, float b) {
    return f2bf(a) | (f2bf(b) << 16);
}
__device__ __forceinline__ short sbf(float f) { return (short)f2bf(f); }

// ---------------------------------------------------------------------------
// data fp32 [N,4] -> bf16 rows (uint2/row)
// ---------------------------------------------------------------------------
__global__ __launch_bounds__(256) void k_cvt(const float* __restrict__ in,
                                             uint4* __restrict__ out) {
    int t = blockIdx.x * 256 + threadIdx.x;
    if (t >= N_PTS * 4 / 8) return;
    const float4* in4 = (const float4*)in;
    float4 a = in4[t * 2], b = in4[t * 2 + 1];
    uint4 o;
    o.x = pk(a.x, a.y); o.y = pk(a.z, a.w);
    o.z = pk(b.x, b.y); o.w = pk(b.z, b.w);
    out[t] = o;
}

// ---------------------------------------------------------------------------
// BN finalize: a = g * rsqrt(var+eps), b = beta - mean*a
// ---------------------------------------------------------------------------
__global__ void k_finalize(const float* __restrict__ sums,
                           const float* __restrict__ g,
                           const float* __restrict__ be,
                           float* __restrict__ ab) {
    int c = threadIdx.x;
    if (c < 16) {
        const float invN = 1.0f / (float)N_PTS;
        float mean = sums[c] * invN;
        float var = sums[16 + c] * invN - mean * mean;
        float a = g[c] * rsqrtf(var + EPS);
        ab[c] = a;
        ab[16 + c] = be[c] - mean * a;
    }
}

// ---------------------------------------------------------------------------
// conv1 via MFMA. A[p][k=j*4+c] = data_bf[ind[p][j]][c], K=36 padded to 64.
// Each lane's A-frag (s=0) = two 8B gathered rows; s=1 = row j=8 (quarter).
// Output y1 bf16 row-major [N][16] via LDS transpose; fused BN1 stats.
// ---------------------------------------------------------------------------
__global__ __launch_bounds__(256) void k_conv1(const uint2* __restrict__ dbf,
                                               const int* __restrict__ ind,
                                               const float* __restrict__ w1,
                                               const float* __restrict__ b1,
                                               uint4* __restrict__ y1,
                                               float* __restrict__ stats) {
    __shared__ float tr[4][64][17];
    __shared__ float red[4][32];
    const int tid = threadIdx.x, lane = tid & 63, wid = tid >> 6;
    const int l15 = lane & 15, lq = lane >> 4;
    const int p0 = blockIdx.x * 256 + wid * 64;

    // B fragments: B[k][o] = w1[c][j][o], k = j*4+c
    bf16x8 B0, B1;
#pragma unroll
    for (int e = 0; e < 8; e++) {
        int k = lq * 8 + e;
        B0[e] = sbf(w1[((k & 3) * 9 + (k >> 2)) * 16 + l15]);
        int k1 = 32 + k;
        B1[e] = (k1 < 36) ? sbf(w1[((k1 & 3) * 9 + (k1 >> 2)) * 16 + l15])
                          : (short)0;
    }
    float bias = b1[l15];
    f32x4 acc[4];
#pragma unroll
    for (int t = 0; t < 4; t++) {
#pragma unroll
        for (int r = 0; r < 4; r++) acc[t][r] = bias;
    }

#pragma unroll
    for (int t = 0; t < 4; t++) {
        int p = p0 + t * 16 + l15;
        int pc = p < N_PTS ? p : N_PTS - 1;
        const int* ib = ind + (size_t)pc * 9;
        // s=0: k in [0,32): rows j = lq*2, lq*2+1 (4 ch each)
        int i0 = ib[lq * 2], i1 = ib[lq * 2 + 1];
        uint2 ra = dbf[i0], rb = dbf[i1];
        bf16x8 A;
        A[0] = (short)ra.x; A[1] = (short)(ra.x >> 16);
        A[2] = (short)ra.y; A[3] = (short)(ra.y >> 16);
        A[4] = (short)rb.x; A[5] = (short)(rb.x >> 16);
        A[6] = (short)rb.y; A[7] = (short)(rb.y >> 16);
        acc[t] = __builtin_amdgcn_mfma_f32_16x16x32_bf16(A, B0, acc[t], 0, 0, 0);
        // s=1: only k in [32,36) valid -> lanes lq==0, elems 0..3 (row j=8)
        bf16x8 A1;
#pragma unroll
        for (int e = 0; e < 8; e++) A1[e] = 0;
        if (lq == 0) {
            int i2 = ib[8];
            uint2 rc = dbf[i2];
            A1[0] = (short)rc.x; A1[1] = (short)(rc.x >> 16);
            A1[2] = (short)rc.y; A1[3] = (short)(rc.y >> 16);
        }
        acc[t] = __builtin_amdgcn_mfma_f32_16x16x32_bf16(A1, B1, acc[t], 0, 0, 0);
    }

    // epilogue: stats + LDS transpose + bf16 row write
    float s = 0.f, ss = 0.f;
#pragma unroll
    for (int t = 0; t < 4; t++) {
#pragma unroll
        for (int r = 0; r < 4; r++) {
            int p = p0 + t * 16 + lq * 4 + r;
            float v = acc[t][r];
            tr[wid][t * 16 + lq * 4 + r][l15] = v;
            if (p < N_PTS) { s += v; ss += v * v; }
        }
    }
    s += __shfl_xor(s, 16);  s += __shfl_xor(s, 32);
    ss += __shfl_xor(ss, 16); ss += __shfl_xor(ss, 32);
    if (lane < 16) { red[wid][lane] = s; red[wid][16 + lane] = ss; }

    int prow = p0 + lane;
    if (prow < N_PTS) {
        float rv[16];
#pragma unroll
        for (int c = 0; c < 16; c++) rv[c] = tr[wid][lane][c];
        uint4 oa, ob;
        oa.x = pk(rv[0], rv[1]);   oa.y = pk(rv[2], rv[3]);
        oa.z = pk(rv[4], rv[5]);   oa.w = pk(rv[6], rv[7]);
        ob.x = pk(rv[8], rv[9]);   ob.y = pk(rv[10], rv[11]);
        ob.z = pk(rv[12], rv[13]); ob.w = pk(rv[14], rv[15]);
        y1[(size_t)prow * 2] = oa;
        y1[(size_t)prow * 2 + 1] = ob;
    }
    __syncthreads();
    if (tid < 32) {
        float v = red[0][tid] + red[1][tid] + red[2][tid] + red[3][tid];
        atomicAdd(&stats[tid], v);
    }
}

// ---------------------------------------------------------------------------
// conv2 via MFMA. A[p][k=j*16+c] = leaky(a1[c]*y1[ind[p][j]][c]+b1[c]).
// K=144 padded to 160 (5 steps). Each A-frag = one gathered 16B half-row,
// affine+leaky applied during unpack. y2 written fp32 row-major into d_out.
// Fused BN2 stats.
// ---------------------------------------------------------------------------
__global__ __launch_bounds__(256) void k_conv2(const uint4* __restrict__ u,
                                               const int* __restrict__ ind,
                                               const float* __restrict__ w2,
                                               const float* __restrict__ ab1,
                                               float* __restrict__ stats,
                                               float4* __restrict__ y2) {
    __shared__ float tr[4][64][17];
    __shared__ float red[4][32];
    const int tid = threadIdx.x, lane = tid & 63, wid = tid >> 6;
    const int l15 = lane & 15, lq = lane >> 4;
    const int jb = lq >> 1, h = lq & 1;
    const int p0 = blockIdx.x * 256 + wid * 64;

    // B fragments: B[k][o] = w2[c][j][o], k = j*16+c, 5 k-steps (pad >=144 -> 0)
    bf16x8 B[5];
#pragma unroll
    for (int s = 0; s < 5; s++) {
#pragma unroll
        for (int e = 0; e < 8; e++) {
            int k = s * 32 + lq * 8 + e;
            short v = 0;
            if (k < 144) v = sbf(w2[((size_t)(k & 15) * 9 + (k >> 4)) * 16 + l15]);
            B[s][e] = v;
        }
    }
    // BN1 affine params for this lane's channel half
    float a1v[8], b1v[8];
#pragma unroll
    for (int e = 0; e < 8; e++) {
        a1v[e] = ab1[h * 8 + e];
        b1v[e] = ab1[16 + h * 8 + e];
    }

    f32x4 acc[4];
#pragma unroll
    for (int t = 0; t < 4; t++) {
#pragma unroll
        for (int r = 0; r < 4; r++) acc[t][r] = 0.f;
    }

#pragma unroll
    for (int t = 0; t < 4; t++) {
        int p = p0 + t * 16 + l15;
        int pc = p < N_PTS ? p : N_PTS - 1;
        const int* ib = ind + (size_t)pc * 9;
#pragma unroll
        for (int s = 0; s < 4; s++) {
            int idx = ib[2 * s + jb];
            uint4 rw = u[(size_t)idx * 2 + h];
            uint vv[4] = {rw.x, rw.y, rw.z, rw.w};
            bf16x8 A;
#pragma unroll
            for (int q = 0; q < 4; q++) {
                float lo = leaky(fmaf(a1v[2 * q], bf2f(vv[q] & 0xffffu), b1v[2 * q]));
                float hi = leaky(fmaf(a1v[2 * q + 1], bf2f(vv[q] >> 16), b1v[2 * q + 1]));
                A[2 * q] = sbf(lo);
                A[2 * q + 1] = sbf(hi);
            }
            acc[t] = __builtin_amdgcn_mfma_f32_16x16x32_bf16(A, B[s], acc[t], 0, 0, 0);
        }
        // tail: k in [128,144) -> j=8, lanes lq<2 (h==lq), others zero
        bf16x8 A4;
#pragma unroll
        for (int e = 0; e < 8; e++) A4[e] = 0;
        if (lq < 2) {
            int idx = ib[8];
            uint4 rw = u[(size_t)idx * 2 + lq];
            uint vv[4] = {rw.x, rw.y, rw.z, rw.w};
#pragma unroll
            for (int q = 0; q < 4; q++) {
                float lo = leaky(fmaf(a1v[2 * q], bf2f(vv[q] & 0xffffu), b1v[2 * q]));
                float hi = leaky(fmaf(a1v[2 * q + 1], bf2f(vv[q] >> 16), b1v[2 * q + 1]));
                A4[2 * q] = sbf(lo);
                A4[2 * q + 1] = sbf(hi);
            }
        }
        acc[t] = __builtin_amdgcn_mfma_f32_16x16x32_bf16(A4, B[4], acc[t], 0, 0, 0);
    }

    // epilogue: stats + LDS transpose + fp32 row write into d_out
    float s = 0.f, ss = 0.f;
#pragma unroll
    for (int t = 0; t < 4; t++) {
#pragma unroll
        for (int r = 0; r < 4; r++) {
            int p = p0 + t * 16 + lq * 4 + r;
            float v = acc[t][r];
            tr[wid][t * 16 + lq * 4 + r][l15] = v;
            if (p < N_PTS) { s += v; ss += v * v; }
        }
    }
    s += __shfl_xor(s, 16);  s += __shfl_xor(s, 32);
    ss += __shfl_xor(ss, 16); ss += __shfl_xor(ss, 32);
    if (lane < 16) { red[wid][lane] = s; red[wid][16 + lane] = ss; }

    int prow = p0 + lane;
    if (prow < N_PTS) {
        float rv[16];
#pragma unroll
        for (int c = 0; c < 16; c++) rv[c] = tr[wid][lane][c];
        float4* row = y2 + (size_t)prow * 4;
        row[0] = make_float4(rv[0], rv[1], rv[2], rv[3]);
        row[1] = make_float4(rv[4], rv[5], rv[6], rv[7]);
        row[2] = make_float4(rv[8], rv[9], rv[10], rv[11]);
        row[3] = make_float4(rv[12], rv[13], rv[14], rv[15]);
    }
    __syncthreads();
    if (tid < 32) {
        float v = red[0][tid] + red[1][tid] + red[2][tid] + red[3][tid];
        atomicAdd(&stats[tid], v);
    }
}

// ---------------------------------------------------------------------------
// final: out[n][o] = leaky(a2[o]*y2[n][o] + b2[o] + sum_c data[n][c]*wd[o][c])
// pure in-place transform of d_out (y2 fp32 rows written by conv2)
// ---------------------------------------------------------------------------
__global__ __launch_bounds__(256) void k_final(float4* __restrict__ y2,
                                               const float* __restrict__ data,
                                               const float* __restrict__ wd,
                                               const float* __restrict__ ab2) {
    __shared__ float wds[64], a2s[16], b2s[16];
    if (threadIdx.x < 64) wds[threadIdx.x] = wd[threadIdx.x];
    if (threadIdx.x < 16) {
        a2s[threadIdx.x] = ab2[threadIdx.x];
        b2s[threadIdx.x] = ab2[16 + threadIdx.x];
    }
    __syncthreads();

    int n = blockIdx.x * 256 + threadIdx.x;
    if (n >= N_PTS) return;

    float4 d = ((const float4*)data)[n];
    float dv[4] = {d.x, d.y, d.z, d.w};
    float4* row = y2 + (size_t)n * 4;
#pragma unroll
    for (int k = 0; k < 4; k++) {
        float4 t = row[k];
        float e[4] = {t.x, t.y, t.z, t.w};
        float r[4];
#pragma unroll
        for (int eo = 0; eo < 4; eo++) {
            int o = k * 4 + eo;
            float res = dv[0] * wds[o * 4 + 0];
            res = fmaf(dv[1], wds[o * 4 + 1], res);
            res = fmaf(dv[2], wds[o * 4 + 2], res);
            res = fmaf(dv[3], wds[o * 4 + 3], res);
            r[eo] = leaky(fmaf(a2s[o], e[eo], b2s[o]) + res);
        }
        row[k] = make_float4(r[0], r[1], r[2], r[3]);
    }
}

extern "C" void kernel_launch(void* const* d_in, const int* in_sizes, int n_in,
                              void* d_out, int out_size, void* d_ws, size_t ws_size,
                              hipStream_t stream) {
    const float* data = (const float*)d_in[0];
    const int* ind    = (const int*)d_in[1];
    const float* w1   = (const float*)d_in[2];
    const float* b1   = (const float*)d_in[3];
    const float* g1   = (const float*)d_in[4];
    const float* be1  = (const float*)d_in[5];
    const float* w2   = (const float*)d_in[6];
    const float* g2   = (const float*)d_in[7];
    const float* be2  = (const float*)d_in[8];
    const float* wd   = (const float*)d_in[9];

    unsigned char* ws = (unsigned char*)d_ws;
    // [0 .. 8e6): data_bf16 rows
    // [8e6 .. 40e6): y1 bf16 rows [N][16]
    // [40e6 .. +512): stats: [0..31] s1, [32..63] ab1, [64..95] s2, [96..127] ab2
    uint4* dbf4  = (uint4*)ws;
    uint2* dbf2  = (uint2*)ws;
    uint4* y1bf  = (uint4*)(ws + 8000000u);
    float* stats = (float*)(ws + 40000000u);

    hipMemsetAsync(stats, 0, 128 * sizeof(float), stream);

    int cvt_blocks = (N_PTS * 4 / 8 + 255) / 256;   // 1954
    int blk        = (N_PTS + 255) / 256;           // 3907

    k_cvt<<<cvt_blocks, 256, 0, stream>>>(data, dbf4);
    k_conv1<<<blk, 256, 0, stream>>>(dbf2, ind, w1, b1, y1bf, stats);
    k_finalize<<<1, 64, 0, stream>>>(stats, g1, be1, stats + 32);
    k_conv2<<<blk, 256, 0, stream>>>(y1bf, ind, w2, stats + 32, stats + 64,
                                     (float4*)d_out);
    k_finalize<<<1, 64, 0, stream>>>(stats + 64, g2, be2, stats + 96);
    k_final<<<blk, 256, 0, stream>>>((float4*)d_out, data, wd, stats + 96);
}

// Round 4
// 309.252 us; speedup vs baseline: 1.9123x; 1.0354x over previous
//
#include <hip/hip_runtime.h>

#define N_PTS 1000000
#define EPS 1e-5f
#define SLOPE 0.2f

typedef __attribute__((ext_vector_type(8))) short bf16x8;
typedef __attribute__((ext_vector_type(4))) float f32x4;

__device__ __forceinline__ float leaky(float x) { return fmaxf(x, SLOPE * x); }
__device__ __forceinline__ float bf2f(unsigned int u) {
    union { unsigned int i; float f; } v; v.i = u << 16; return v.f;
}
__device__ __forceinline__ unsigned int f2bf(float f) {
    union { float f; unsigned int i; } v; v.f = f;
    return (v.i + 0x7fffu + ((v.i >> 16) & 1u)) >> 16;
}
__device__ __forceinline__ unsigned int pk(float a, float b) {
    return f2bf(a) | (f2bf(b) << 16);
}
__device__ __forceinline__ short sbf(float f) { return (short)f2bf(f); }
__device__ __forceinline__ bf16x8 asfrag(uint4 r) {
    union { uint4 u; bf16x8 f; } v; v.u = r; return v.f;
}

// ---------------------------------------------------------------------------
// data fp32 [N,4] -> bf16 rows (uint2/row)
// ---------------------------------------------------------------------------
__global__ __launch_bounds__(256) void k_cvt(const float* __restrict__ in,
                                             uint4* __restrict__ out) {
    int t = blockIdx.x * 256 + threadIdx.x;
    if (t >= N_PTS * 4 / 8) return;
    const float4* in4 = (const float4*)in;
    float4 a = in4[t * 2], b = in4[t * 2 + 1];
    uint4 o;
    o.x = pk(a.x, a.y); o.y = pk(a.z, a.w);
    o.z = pk(b.x, b.y); o.w = pk(b.z, b.w);
    out[t] = o;
}

// ---------------------------------------------------------------------------
// conv1 via MFMA. A[p][k=j*4+c] = data_bf[ind[p][j]][c], K=36 -> 2 k-steps.
// All idx + rows staged up front. Output y1 bf16 [N][16]; fused BN1 stats.
// ---------------------------------------------------------------------------
__global__ __launch_bounds__(256) void k_conv1(const uint2* __restrict__ dbf,
                                               const int* __restrict__ ind,
                                               const float* __restrict__ w1,
                                               const float* __restrict__ b1,
                                               uint4* __restrict__ y1,
                                               float* __restrict__ stats) {
    __shared__ float tr[4][64][17];
    __shared__ float red[4][32];
    const int tid = threadIdx.x, lane = tid & 63, wid = tid >> 6;
    const int l15 = lane & 15, lq = lane >> 4;
    const int p0 = blockIdx.x * 256 + wid * 64;

    // B fragments: B[k][o] = w1[c][j][o], k = j*4+c
    bf16x8 B0, B1;
#pragma unroll
    for (int e = 0; e < 8; e++) {
        int k = lq * 8 + e;
        B0[e] = sbf(w1[((k & 3) * 9 + (k >> 2)) * 16 + l15]);
        int k1 = 32 + k;
        B1[e] = (k1 < 36) ? sbf(w1[((k1 & 3) * 9 + (k1 >> 2)) * 16 + l15])
                          : (short)0;
    }
    float bias = b1[l15];
    f32x4 acc[4];
#pragma unroll
    for (int t = 0; t < 4; t++) {
#pragma unroll
        for (int r = 0; r < 4; r++) acc[t][r] = bias;
    }

    // stage all indices
    int id0[4], id1[4], id8[4];
#pragma unroll
    for (int t = 0; t < 4; t++) {
        int p = p0 + t * 16 + l15;
        int pc = p < N_PTS ? p : N_PTS - 1;
        const int* ib = ind + (size_t)pc * 9;
        id0[t] = ib[lq * 2];
        id1[t] = ib[lq * 2 + 1];
        id8[t] = ib[8];
    }
    // stage all rows
    uint2 ra[4], rb[4], rc[4];
#pragma unroll
    for (int t = 0; t < 4; t++) {
        ra[t] = dbf[id0[t]];
        rb[t] = dbf[id1[t]];
        rc[t] = dbf[id8[t]];
    }

#pragma unroll
    for (int t = 0; t < 4; t++) {
        bf16x8 A;
        A[0] = (short)ra[t].x; A[1] = (short)(ra[t].x >> 16);
        A[2] = (short)ra[t].y; A[3] = (short)(ra[t].y >> 16);
        A[4] = (short)rb[t].x; A[5] = (short)(rb[t].x >> 16);
        A[6] = (short)rb[t].y; A[7] = (short)(rb[t].y >> 16);
        acc[t] = __builtin_amdgcn_mfma_f32_16x16x32_bf16(A, B0, acc[t], 0, 0, 0);
        bf16x8 A1;
#pragma unroll
        for (int e = 0; e < 8; e++) A1[e] = 0;
        if (lq == 0) {
            A1[0] = (short)rc[t].x; A1[1] = (short)(rc[t].x >> 16);
            A1[2] = (short)rc[t].y; A1[3] = (short)(rc[t].y >> 16);
        }
        acc[t] = __builtin_amdgcn_mfma_f32_16x16x32_bf16(A1, B1, acc[t], 0, 0, 0);
    }

    // epilogue: stats + LDS transpose + bf16 row write
    float s = 0.f, ss = 0.f;
#pragma unroll
    for (int t = 0; t < 4; t++) {
#pragma unroll
        for (int r = 0; r < 4; r++) {
            int p = p0 + t * 16 + lq * 4 + r;
            float v = acc[t][r];
            tr[wid][t * 16 + lq * 4 + r][l15] = v;
            if (p < N_PTS) { s += v; ss += v * v; }
        }
    }
    s += __shfl_xor(s, 16);  s += __shfl_xor(s, 32);
    ss += __shfl_xor(ss, 16); ss += __shfl_xor(ss, 32);
    if (lane < 16) { red[wid][lane] = s; red[wid][16 + lane] = ss; }

    int prow = p0 + lane;
    if (prow < N_PTS) {
        float rv[16];
#pragma unroll
        for (int c = 0; c < 16; c++) rv[c] = tr[wid][lane][c];
        uint4 oa, ob;
        oa.x = pk(rv[0], rv[1]);   oa.y = pk(rv[2], rv[3]);
        oa.z = pk(rv[4], rv[5]);   oa.w = pk(rv[6], rv[7]);
        ob.x = pk(rv[8], rv[9]);   ob.y = pk(rv[10], rv[11]);
        ob.z = pk(rv[12], rv[13]); ob.w = pk(rv[14], rv[15]);
        y1[(size_t)prow * 2] = oa;
        y1[(size_t)prow * 2 + 1] = ob;
    }
    __syncthreads();
    if (tid < 32) {
        float v = red[0][tid] + red[1][tid] + red[2][tid] + red[3][tid];
        atomicAdd(&stats[tid], v);
    }
}

// ---------------------------------------------------------------------------
// k_act: in-place BN1 affine + leaky on y1 bf16 (finalize inlined per block).
// One uint4 = half a row (8 channels, half h = i&1).
// ---------------------------------------------------------------------------
__global__ __launch_bounds__(256) void k_act(uint4* __restrict__ y1,
                                             const float* __restrict__ stats,
                                             const float* __restrict__ g,
                                             const float* __restrict__ be) {
    __shared__ float as_[16], bs_[16];
    if (threadIdx.x < 16) {
        int c = threadIdx.x;
        const float invN = 1.0f / (float)N_PTS;
        float mean = stats[c] * invN;
        float var = stats[16 + c] * invN - mean * mean;
        float a = g[c] * rsqrtf(var + EPS);
        as_[c] = a;
        bs_[c] = be[c] - mean * a;
    }
    __syncthreads();

    const size_t total = (size_t)N_PTS * 2;
    size_t i = (size_t)blockIdx.x * 256 + threadIdx.x;
    size_t stride = (size_t)gridDim.x * 256;
    for (; i < total; i += stride) {
        int h = (int)(i & 1);
        uint4 u = y1[i];
        uint vv[4] = {u.x, u.y, u.z, u.w};
        uint4 o;
        uint ov[4];
#pragma unroll
        for (int q = 0; q < 4; q++) {
            int c = h * 8 + 2 * q;
            float lo = leaky(fmaf(as_[c], bf2f(vv[q] & 0xffffu), bs_[c]));
            float hi = leaky(fmaf(as_[c + 1], bf2f(vv[q] >> 16), bs_[c + 1]));
            ov[q] = pk(lo, hi);
        }
        o.x = ov[0]; o.y = ov[1]; o.z = ov[2]; o.w = ov[3];
        y1[i] = o;
    }
}

// ---------------------------------------------------------------------------
// conv2 via MFMA. A[p][k=j*16+c] = y1a[ind[p][j]][c] (pre-activated).
// K=144 -> 5 k-steps. Gathered 16B half-rows feed MFMA directly.
// Software-pipelined 2 t-iterations deep. Fused BN2 stats. y2 fp32 -> d_out.
// ---------------------------------------------------------------------------
__global__ __launch_bounds__(256) void k_conv2(const uint4* __restrict__ u,
                                               const int* __restrict__ ind,
                                               const float* __restrict__ w2,
                                               float* __restrict__ stats,
                                               float4* __restrict__ y2) {
    __shared__ float tr[4][64][17];
    __shared__ float red[4][32];
    const int tid = threadIdx.x, lane = tid & 63, wid = tid >> 6;
    const int l15 = lane & 15, lq = lane >> 4;
    const int jb = lq >> 1, h = lq & 1;
    const int p0 = blockIdx.x * 256 + wid * 64;

    // B fragments: B[k][o] = w2[c][j][o], k = j*16+c (zero-pad k>=144)
    bf16x8 B[5];
#pragma unroll
    for (int s = 0; s < 5; s++) {
#pragma unroll
        for (int e = 0; e < 8; e++) {
            int k = s * 32 + lq * 8 + e;
            short v = 0;
            if (k < 144) v = sbf(w2[((size_t)(k & 15) * 9 + (k >> 4)) * 16 + l15]);
            B[s][e] = v;
        }
    }

    f32x4 acc[4];
#pragma unroll
    for (int t = 0; t < 4; t++) {
#pragma unroll
        for (int r = 0; r < 4; r++) acc[t][r] = 0.f;
    }

    // stage all indices
    int idm[4][5];
#pragma unroll
    for (int t = 0; t < 4; t++) {
        int p = p0 + t * 16 + l15;
        int pc = p < N_PTS ? p : N_PTS - 1;
        const int* ib = ind + (size_t)pc * 9;
#pragma unroll
        for (int s = 0; s < 4; s++) idm[t][s] = ib[2 * s + jb];
        idm[t][4] = ib[8];
    }

    uint4 r0[5], r1[5];
#define LOADT(dst, t)                                                     \
    do {                                                                  \
        dst[0] = u[(size_t)idm[t][0] * 2 + h];                            \
        dst[1] = u[(size_t)idm[t][1] * 2 + h];                            \
        dst[2] = u[(size_t)idm[t][2] * 2 + h];                            \
        dst[3] = u[(size_t)idm[t][3] * 2 + h];                            \
        dst[4] = u[(size_t)idm[t][4] * 2 + h];                            \
    } while (0)

    bf16x8 zf;
#pragma unroll
    for (int e = 0; e < 8; e++) zf[e] = 0;

#define COMPT(t, src)                                                     \
    do {                                                                  \
        acc[t] = __builtin_amdgcn_mfma_f32_16x16x32_bf16(asfrag(src[0]), B[0], acc[t], 0, 0, 0); \
        acc[t] = __builtin_amdgcn_mfma_f32_16x16x32_bf16(asfrag(src[1]), B[1], acc[t], 0, 0, 0); \
        acc[t] = __builtin_amdgcn_mfma_f32_16x16x32_bf16(asfrag(src[2]), B[2], acc[t], 0, 0, 0); \
        acc[t] = __builtin_amdgcn_mfma_f32_16x16x32_bf16(asfrag(src[3]), B[3], acc[t], 0, 0, 0); \
        bf16x8 A4 = (lq < 2) ? asfrag(src[4]) : zf;                       \
        acc[t] = __builtin_amdgcn_mfma_f32_16x16x32_bf16(A4, B[4], acc[t], 0, 0, 0); \
    } while (0)

    LOADT(r0, 0);
    LOADT(r1, 1);
    COMPT(0, r0);
    LOADT(r0, 2);
    COMPT(1, r1);
    LOADT(r1, 3);
    COMPT(2, r0);
    COMPT(3, r1);
#undef LOADT
#undef COMPT

    // epilogue: stats + LDS transpose + fp32 row write into d_out
    float s = 0.f, ss = 0.f;
#pragma unroll
    for (int t = 0; t < 4; t++) {
#pragma unroll
        for (int r = 0; r < 4; r++) {
            int p = p0 + t * 16 + lq * 4 + r;
            float v = acc[t][r];
            tr[wid][t * 16 + lq * 4 + r][l15] = v;
            if (p < N_PTS) { s += v; ss += v * v; }
        }
    }
    s += __shfl_xor(s, 16);  s += __shfl_xor(s, 32);
    ss += __shfl_xor(ss, 16); ss += __shfl_xor(ss, 32);
    if (lane < 16) { red[wid][lane] = s; red[wid][16 + lane] = ss; }

    int prow = p0 + lane;
    if (prow < N_PTS) {
        float rv[16];
#pragma unroll
        for (int c = 0; c < 16; c++) rv[c] = tr[wid][lane][c];
        float4* row = y2 + (size_t)prow * 4;
        row[0] = make_float4(rv[0], rv[1], rv[2], rv[3]);
        row[1] = make_float4(rv[4], rv[5], rv[6], rv[7]);
        row[2] = make_float4(rv[8], rv[9], rv[10], rv[11]);
        row[3] = make_float4(rv[12], rv[13], rv[14], rv[15]);
    }
    __syncthreads();
    if (tid < 32) {
        float v = red[0][tid] + red[1][tid] + red[2][tid] + red[3][tid];
        atomicAdd(&stats[tid], v);
    }
}

// ---------------------------------------------------------------------------
// final: out[n][o] = leaky(a2[o]*y2[n][o] + b2[o] + sum_c data[n][c]*wd[o][c])
// in-place on d_out; BN2 finalize inlined per block.
// ---------------------------------------------------------------------------
__global__ __launch_bounds__(256) void k_final(float4* __restrict__ y2,
                                               const float* __restrict__ data,
                                               const float* __restrict__ wd,
                                               const float* __restrict__ stats,
                                               const float* __restrict__ g,
                                               const float* __restrict__ be) {
    __shared__ float wds[64], a2s[16], b2s[16];
    if (threadIdx.x < 64) wds[threadIdx.x] = wd[threadIdx.x];
    if (threadIdx.x < 16) {
        int c = threadIdx.x;
        const float invN = 1.0f / (float)N_PTS;
        float mean = stats[c] * invN;
        float var = stats[16 + c] * invN - mean * mean;
        float a = g[c] * rsqrtf(var + EPS);
        a2s[c] = a;
        b2s[c] = be[c] - mean * a;
    }
    __syncthreads();

    int n = blockIdx.x * 256 + threadIdx.x;
    if (n >= N_PTS) return;

    float4 d = ((const float4*)data)[n];
    float dv[4] = {d.x, d.y, d.z, d.w};
    float4* row = y2 + (size_t)n * 4;
#pragma unroll
    for (int k = 0; k < 4; k++) {
        float4 t = row[k];
        float e[4] = {t.x, t.y, t.z, t.w};
        float r[4];
#pragma unroll
        for (int eo = 0; eo < 4; eo++) {
            int o = k * 4 + eo;
            float res = dv[0] * wds[o * 4 + 0];
            res = fmaf(dv[1], wds[o * 4 + 1], res);
            res = fmaf(dv[2], wds[o * 4 + 2], res);
            res = fmaf(dv[3], wds[o * 4 + 3], res);
            r[eo] = leaky(fmaf(a2s[o], e[eo], b2s[o]) + res);
        }
        row[k] = make_float4(r[0], r[1], r[2], r[3]);
    }
}

extern "C" void kernel_launch(void* const* d_in, const int* in_sizes, int n_in,
                              void* d_out, int out_size, void* d_ws, size_t ws_size,
                              hipStream_t stream) {
    const float* data = (const float*)d_in[0];
    const int* ind    = (const int*)d_in[1];
    const float* w1   = (const float*)d_in[2];
    const float* b1   = (const float*)d_in[3];
    const float* g1   = (const float*)d_in[4];
    const float* be1  = (const float*)d_in[5];
    const float* w2   = (const float*)d_in[6];
    const float* g2   = (const float*)d_in[7];
    const float* be2  = (const float*)d_in[8];
    const float* wd   = (const float*)d_in[9];

    unsigned char* ws = (unsigned char*)d_ws;
    // [0 .. 8e6): data_bf16 rows
    // [8e6 .. 40e6): y1 bf16 rows [N][16] (activated in place by k_act)
    // [40e6 .. +256): stats: [0..31] s1, [32..63] s2
    uint4* dbf4  = (uint4*)ws;
    uint2* dbf2  = (uint2*)ws;
    uint4* y1bf  = (uint4*)(ws + 8000000u);
    float* stats = (float*)(ws + 40000000u);

    hipMemsetAsync(stats, 0, 64 * sizeof(float), stream);

    int cvt_blocks = (N_PTS * 4 / 8 + 255) / 256;   // 1954
    int blk        = (N_PTS + 255) / 256;           // 3907

    k_cvt<<<cvt_blocks, 256, 0, stream>>>(data, dbf4);
    k_conv1<<<blk, 256, 0, stream>>>(dbf2, ind, w1, b1, y1bf, stats);
    k_act<<<2048, 256, 0, stream>>>(y1bf, stats, g1, be1);
    k_conv2<<<blk, 256, 0, stream>>>(y1bf, ind, w2, stats + 32, (float4*)d_out);
    k_final<<<blk, 256, 0, stream>>>((float4*)d_out, data, wd, stats + 32, g2, be2);
}